// Round 5
// baseline (825.193 us; speedup 1.0000x reference)
//
#include <hip/hip_runtime.h>

// ---------------------------------------------------------------------------
// TransformerBlock: B=2 T=2048 C=2048 H=16 HD=128 MLP=8192, causal, relu^2 MLP
// Round 9: 8-phase core templated over tile height MH (BM=64*MH, BN=256,
// BK=64, 8 waves, counted vmcnt, raw s_barrier, setprio, XOR slot swizzle).
//   fc1: MH=4 (256x256), grid 512 = 2.0 rounds
//   qkv: MH=2 (128x256), grid 768 = 3.0 rounds  (fixes 1.5-round tail)
//   wo/fc2: MH=2 (128x256), grid 256 = 1.0 round (counted-vmcnt vs 2-phase)
//
// mfma_f32_16x16x32_bf16 layouts (learn_hip m89/m91):
//   A[m=lane&15][k=(lane>>4)*8+j], B[n=lane&15][k=(lane>>4)*8+j]
//   D[row=(lane>>4)*4+reg][col=lane&15]
//
// Workspace (184.5 MB, proven):
//   flag(256B) | h | qb | kb | vt | ao | x1(f32) | mm(2*FCE bf16)
// Aliases: wqkvo_b=mm (dead until fc1 GEMM), fc1b=qb..kb (after attn),
//          fc2b=vt..ao (after wo GEMM).
// ---------------------------------------------------------------------------

typedef __bf16 bf16x8 __attribute__((ext_vector_type(8)));
typedef __bf16 bf16x4 __attribute__((ext_vector_type(4)));
typedef float  f32x4  __attribute__((ext_vector_type(4)));

static __device__ __forceinline__ __bf16 tobf(float f) { return (__bf16)f; }

// async 16B global->LDS; lptr wave-uniform, HW writes lane l at lptr + l*16.
static __device__ __forceinline__ void async_copy16(const void* g, void* l) {
    __builtin_amdgcn_global_load_lds(
        (const __attribute__((address_space(1))) void*)g,
        (__attribute__((address_space(3))) void*)l, 16, 0, 0);
}

// memory-clobber pins memory ops to their phase; register-only MFMA stays
// schedulable (R3->R4 lesson: NO sched_barrier here).
#define LGKM0_FENCE()  asm volatile("s_waitcnt lgkmcnt(0)" ::: "memory")

// ---------------------------------------------------------------------------
__global__ void detect_dtype_kernel(const unsigned short* __restrict__ xh,
                                    int* __restrict__ flag) {
    int t = threadIdx.x;                       // one wave of 64
    unsigned short u = xh[2 * t];              // even ushort slots
    int e = (u >> 7) & 0xFF;                   // bf16 exponent field
    bool outlier = (e < 100) || (e > 131);     // implausible for N(0,1)
    unsigned long long m = __ballot(outlier);
    if (t == 0) *flag = (__popcll(m) >= 16) ? 1 : 0;   // 1 => fp32 buffers
}

// ---------------------------------------------------------------------------
// Weight conversion, 8 elems/thread.
__global__ __launch_bounds__(256) void convert_w4(
    const void* __restrict__ w0, const void* __restrict__ w1,
    const void* __restrict__ w2, const void* __restrict__ w3,
    __bf16* __restrict__ dqkvo, const int* __restrict__ flagp) {
    constexpr size_t CC = (size_t)2048 * 2048;
    const int y = blockIdx.y;
    size_t i = ((size_t)blockIdx.x * 256 + threadIdx.x) * 8;
    const void* s = (y == 0) ? w0 : (y == 1) ? w1 : (y == 2) ? w2 : w3;
    __bf16* d = dqkvo + (size_t)y * CC;
    if (*flagp != 0) {
        const float4* sp = (const float4*)((const float*)s + i);
        float4 a = sp[0], b = sp[1];
        bf16x8 o = {tobf(a.x), tobf(a.y), tobf(a.z), tobf(a.w),
                    tobf(b.x), tobf(b.y), tobf(b.z), tobf(b.w)};
        *(bf16x8*)(d + i) = o;
    } else {
        *(bf16x8*)(d + i) = *(const bf16x8*)((const __bf16*)s + i);
    }
}

__global__ __launch_bounds__(256) void convert_w1(
    const void* __restrict__ src, __bf16* __restrict__ dst,
    const int* __restrict__ flagp) {
    size_t i = ((size_t)blockIdx.x * 256 + threadIdx.x) * 8;
    if (*flagp != 0) {
        const float4* sp = (const float4*)((const float*)src + i);
        float4 a = sp[0], b = sp[1];
        bf16x8 o = {tobf(a.x), tobf(a.y), tobf(a.z), tobf(a.w),
                    tobf(b.x), tobf(b.y), tobf(b.z), tobf(b.w)};
        *(bf16x8*)(dst + i) = o;
    } else {
        *(bf16x8*)(dst + i) = *(const bf16x8*)((const __bf16*)src + i);
    }
}

// ---------------------------------------------------------------------------
// rmsnorm: row of C=2048, one block per row, 256 threads x 8 elements.
template <int SRC>
__global__ __launch_bounds__(256) void rmsnorm_kernel(
    const void* __restrict__ xp, __bf16* __restrict__ h,
    const int* __restrict__ flagp) {
    constexpr int C = 2048;
    const int row = blockIdx.x, t = threadIdx.x;
    float vals[8];
    bool f32in = (SRC == 1) || (*flagp != 0);
    if (f32in) {
        const float4* xr = (const float4*)((const float*)xp + (size_t)row * C);
        float4 a = xr[2 * t], b = xr[2 * t + 1];
        vals[0] = a.x; vals[1] = a.y; vals[2] = a.z; vals[3] = a.w;
        vals[4] = b.x; vals[5] = b.y; vals[6] = b.z; vals[7] = b.w;
    } else {
        bf16x8 a = *((const bf16x8*)((const __bf16*)xp + (size_t)row * C) + t);
#pragma unroll
        for (int j = 0; j < 8; ++j) vals[j] = (float)a[j];
    }
    float ss = 0.f;
#pragma unroll
    for (int j = 0; j < 8; ++j) ss += vals[j] * vals[j];
#pragma unroll
    for (int off = 32; off > 0; off >>= 1) ss += __shfl_down(ss, off);
    __shared__ float red[4];
    if ((t & 63) == 0) red[t >> 6] = ss;
    __syncthreads();
    float mean = (red[0] + red[1] + red[2] + red[3]) * (1.0f / C);
    float sc = rsqrtf(mean + 1e-5f);
    bf16x8 o;
#pragma unroll
    for (int j = 0; j < 8; ++j) o[j] = tobf(vals[j] * sc);
    *((bf16x8*)(h + (size_t)row * C) + t) = o;
}

// ---------------------------------------------------------------------------
// 8-phase GEMM core, BM = 64*MH x BN = 256, BK=64, 512 threads (8 waves, 2Mx4N).
// Double-buffered LDS with XOR slot swizzle (phys slot = logical ^ (row&7));
// global_load_lds dest linear, source pre-swizzled, reads swizzled.
// Phases per K-tile t (buffer bi = t&1):
//   Q0: ds_read a0(m 0..MH-1)+b0(n0-1)          ; mfma a0xb0
//   Q1: ds_read a1(m MH..2MH-1)                 ; mfma a1xb0
//   Q2: ds_read b1(n2-3); stage A(t+2)->bi      ; mfma a1xb1
//   Q3: stage B(t+2)->bi                        ; mfma a0xb1 ; vmcnt(MH+4)
// Each phase: reads/stage, s_barrier, lgkmcnt(0), setprio(1) MFMA setprio(0),
// s_barrier. A rows of tile t fully read chip-wide after Q1's trailing
// barrier; B rows after Q2's. vmcnt(MH+4) leaves exactly tile t+2's loads in
// flight => tile t+1 landed.
template <int MH>
static __device__ __forceinline__ void gemm_core_8ph(
    const __bf16* __restrict__ A, const __bf16* __restrict__ W,
    int m0, int n0, int K, __bf16* __restrict__ AsB, __bf16* __restrict__ BsB,
    f32x4 (&acc)[2 * MH][4]) {
    constexpr int BM = 64 * MH;
    constexpr int ASTRIDE = BM * 64;        // elems per A buffer
    constexpr int BSTRIDE = 256 * 64;       // elems per B buffer
    const int tid = threadIdx.x;
    const int wave = tid >> 6, lane = tid & 63;
    const int lr = lane & 15, lq = lane >> 4;
    const int wm = wave >> 2, wn = wave & 3;
    const int sx = lr & 7;
    const int NT = K >> 6;

    // staging chunk maps: A = MH chunks/thread, B = 4 chunks/thread.
    int offA[MH], loA[MH], offB[4], loB[4];
#pragma unroll
    for (int i = 0; i < MH; ++i) {
        int c = i * 512 + tid;
        int row = c >> 3;
        offA[i] = row * K + (((c & 7) ^ (row & 7)) * 8);
        loA[i] = (c & ~63) * 8;
    }
#pragma unroll
    for (int i = 0; i < 4; ++i) {
        int c = i * 512 + tid;
        int row = c >> 3;
        offB[i] = row * K + (((c & 7) ^ (row & 7)) * 8);
        loB[i] = (c & ~63) * 8;
    }

    const f32x4 zero = {0.f, 0.f, 0.f, 0.f};
#pragma unroll
    for (int m = 0; m < 2 * MH; ++m)
#pragma unroll
        for (int n = 0; n < 4; ++n) acc[m][n] = zero;

    // prologue: stage tiles 0 (buf0) and 1 (buf1); wait tile0.
#pragma unroll
    for (int pt = 0; pt < 2; ++pt) {
        const __bf16* ga = A + (size_t)m0 * K + pt * 64;
        const __bf16* gb = W + (size_t)n0 * K + pt * 64;
        __bf16* la = AsB + pt * ASTRIDE;
        __bf16* lb = BsB + pt * BSTRIDE;
#pragma unroll
        for (int i = 0; i < MH; ++i) async_copy16(ga + offA[i], la + loA[i]);
#pragma unroll
        for (int i = 0; i < 4; ++i)  async_copy16(gb + offB[i], lb + loB[i]);
    }
    if constexpr (MH == 4) asm volatile("s_waitcnt vmcnt(8)" ::: "memory");
    else                   asm volatile("s_waitcnt vmcnt(6)" ::: "memory");
    __builtin_amdgcn_s_barrier();

    for (int t = 0; t < NT; ++t) {
        const int bi = t & 1;
        const __bf16* Ac = AsB + bi * ASTRIDE;
        const __bf16* Bc = BsB + bi * BSTRIDE;
        const int ts = (t + 2 < NT) ? t + 2 : NT - 1;   // clamp: safe dummy
        const __bf16* gAt = A + (size_t)m0 * K + (size_t)ts * 64;
        const __bf16* gBt = W + (size_t)n0 * K + (size_t)ts * 64;

        bf16x8 a0[MH][2], a1[MH][2], b0[2][2], b1[2][2];

        // ---- Q0: read a0 + b0; mfma a0 x b0 ----
#pragma unroll
        for (int m = 0; m < MH; ++m)
#pragma unroll
            for (int kk = 0; kk < 2; ++kk)
                a0[m][kk] = *(const bf16x8*)
                    &Ac[(wm * (32 * MH) + m * 16 + lr) * 64 +
                        ((kk * 4 + lq) ^ sx) * 8];
#pragma unroll
        for (int n = 0; n < 2; ++n)
#pragma unroll
            for (int kk = 0; kk < 2; ++kk)
                b0[n][kk] = *(const bf16x8*)
                    &Bc[(wn * 64 + n * 16 + lr) * 64 +
                        ((kk * 4 + lq) ^ sx) * 8];
        __builtin_amdgcn_s_barrier();
        LGKM0_FENCE();
        __builtin_amdgcn_s_setprio(1);
#pragma unroll
        for (int m = 0; m < MH; ++m)
#pragma unroll
            for (int n = 0; n < 2; ++n)
#pragma unroll
                for (int kk = 0; kk < 2; ++kk)
                    acc[m][n] = __builtin_amdgcn_mfma_f32_16x16x32_bf16(
                        a0[m][kk], b0[n][kk], acc[m][n], 0, 0, 0);
        __builtin_amdgcn_s_setprio(0);
        __builtin_amdgcn_s_barrier();

        // ---- Q1: read a1; mfma a1 x b0 ----
#pragma unroll
        for (int m = 0; m < MH; ++m)
#pragma unroll
            for (int kk = 0; kk < 2; ++kk)
                a1[m][kk] = *(const bf16x8*)
                    &Ac[(wm * (32 * MH) + (m + MH) * 16 + lr) * 64 +
                        ((kk * 4 + lq) ^ sx) * 8];
        __builtin_amdgcn_s_barrier();
        LGKM0_FENCE();
        __builtin_amdgcn_s_setprio(1);
#pragma unroll
        for (int m = 0; m < MH; ++m)
#pragma unroll
            for (int n = 0; n < 2; ++n)
#pragma unroll
                for (int kk = 0; kk < 2; ++kk)
                    acc[m + MH][n] = __builtin_amdgcn_mfma_f32_16x16x32_bf16(
                        a1[m][kk], b0[n][kk], acc[m + MH][n], 0, 0, 0);
        __builtin_amdgcn_s_setprio(0);
        __builtin_amdgcn_s_barrier();
        // (A rows of tile t ds_read-complete chip-wide here)

        // ---- Q2: read b1; stage A(t+2)->bi; mfma a1 x b1 ----
#pragma unroll
        for (int n = 0; n < 2; ++n)
#pragma unroll
            for (int kk = 0; kk < 2; ++kk)
                b1[n][kk] = *(const bf16x8*)
                    &Bc[(wn * 64 + (n + 2) * 16 + lr) * 64 +
                        ((kk * 4 + lq) ^ sx) * 8];
#pragma unroll
        for (int i = 0; i < MH; ++i)
            async_copy16(gAt + offA[i], AsB + bi * ASTRIDE + loA[i]);
        __builtin_amdgcn_s_barrier();
        LGKM0_FENCE();
        __builtin_amdgcn_s_setprio(1);
#pragma unroll
        for (int m = 0; m < MH; ++m)
#pragma unroll
            for (int n = 0; n < 2; ++n)
#pragma unroll
                for (int kk = 0; kk < 2; ++kk)
                    acc[m + MH][n + 2] = __builtin_amdgcn_mfma_f32_16x16x32_bf16(
                        a1[m][kk], b1[n][kk], acc[m + MH][n + 2], 0, 0, 0);
        __builtin_amdgcn_s_setprio(0);
        __builtin_amdgcn_s_barrier();
        // (B rows of tile t ds_read-complete chip-wide here)

        // ---- Q3: stage B(t+2)->bi; mfma a0 x b1; counted vmcnt ----
#pragma unroll
        for (int i = 0; i < 4; ++i)
            async_copy16(gBt + offB[i], BsB + bi * BSTRIDE + loB[i]);
        __builtin_amdgcn_s_barrier();
        __builtin_amdgcn_s_setprio(1);
#pragma unroll
        for (int m = 0; m < MH; ++m)
#pragma unroll
            for (int n = 0; n < 2; ++n)
#pragma unroll
                for (int kk = 0; kk < 2; ++kk)
                    acc[m][n + 2] = __builtin_amdgcn_mfma_f32_16x16x32_bf16(
                        a0[m][kk], b1[n][kk], acc[m][n + 2], 0, 0, 0);
        __builtin_amdgcn_s_setprio(0);
        if constexpr (MH == 4) asm volatile("s_waitcnt vmcnt(8)" ::: "memory");
        else                   asm volatile("s_waitcnt vmcnt(6)" ::: "memory");
        __builtin_amdgcn_s_barrier();
    }
}

// ---------------------------------------------------------------------------
// 256^2 NT GEMM (8-phase, MH=4). EPI 2: bf16 relu(acc)^2 (fc1).
template <int EPI>
__global__ __launch_bounds__(512, 1) void gemm256_nt(
    const __bf16* __restrict__ A, const __bf16* __restrict__ W,
    void* __restrict__ outp, const void* __restrict__ resp,
    int M, int N, int K, const int* __restrict__ flagp) {
    __shared__ __align__(16) __bf16 As[2][256][64];
    __shared__ __align__(16) __bf16 Bs[2][256][64];
    const int tid = threadIdx.x;
    const int wave = tid >> 6, lane = tid & 63;
    const int lr = lane & 15, lq = lane >> 4;
    const int wm = wave >> 2, wn = wave & 3;
    const int m0 = blockIdx.y * 256, n0 = blockIdx.x * 256;

    f32x4 acc[8][4];
    gemm_core_8ph<4>(A, W, m0, n0, K, &As[0][0][0], &Bs[0][0][0], acc);

    const bool f32 = (EPI == 2) ? false : (*flagp != 0);
#pragma unroll
    for (int m = 0; m < 8; ++m)
#pragma unroll
        for (int n = 0; n < 4; ++n)
#pragma unroll
            for (int r = 0; r < 4; ++r) {
                int row = m0 + wm * 128 + m * 16 + lq * 4 + r;
                int col = n0 + wn * 64 + n * 16 + lr;
                size_t o = (size_t)row * N + col;
                float v = acc[m][n][r];
                if (EPI == 2) {
                    float rv = v > 0.f ? v : 0.f;
                    ((__bf16*)outp)[o] = tobf(rv * rv);
                } else if (EPI == 5) {
                    float res = f32 ? ((const float*)resp)[o]
                                    : (float)((const __bf16*)resp)[o];
                    ((float*)outp)[o] = v + res;
                } else {  // EPI 6
                    float ov = v + ((const float*)resp)[o];
                    if (f32) ((float*)outp)[o] = ov;
                    else     ((__bf16*)outp)[o] = tobf(ov);
                }
            }
}

// ---------------------------------------------------------------------------
// 128x256 NT GEMM (8-phase, MH=2). EPI 5: fp32 out=acc+res (wo);
// EPI 6: out=acc+res_f32, out dtype per flag (fc2).
template <int EPI>
__global__ __launch_bounds__(512, 1) void gemm128_nt(
    const __bf16* __restrict__ A, const __bf16* __restrict__ W,
    void* __restrict__ outp, const void* __restrict__ resp,
    int M, int N, int K, const int* __restrict__ flagp) {
    __shared__ __align__(16) __bf16 As[2][128][64];
    __shared__ __align__(16) __bf16 Bs[2][256][64];
    const int tid = threadIdx.x;
    const int wave = tid >> 6, lane = tid & 63;
    const int lr = lane & 15, lq = lane >> 4;
    const int wm = wave >> 2, wn = wave & 3;
    const int m0 = blockIdx.y * 128, n0 = blockIdx.x * 256;

    f32x4 acc[4][4];
    gemm_core_8ph<2>(A, W, m0, n0, K, &As[0][0][0], &Bs[0][0][0], acc);

    const bool f32 = (*flagp != 0);
#pragma unroll
    for (int m = 0; m < 4; ++m)
#pragma unroll
        for (int n = 0; n < 4; ++n)
#pragma unroll
            for (int r = 0; r < 4; ++r) {
                int row = m0 + wm * 64 + m * 16 + lq * 4 + r;
                int col = n0 + wn * 64 + n * 16 + lr;
                size_t o = (size_t)row * N + col;
                float v = acc[m][n][r];
                if (EPI == 5) {
                    float res = f32 ? ((const float*)resp)[o]
                                    : (float)((const __bf16*)resp)[o];
                    ((float*)outp)[o] = v + res;
                } else {  // EPI 6
                    float ov = v + ((const float*)resp)[o];
                    if (f32) ((float*)outp)[o] = ov;
                    else     ((__bf16*)outp)[o] = tobf(ov);
                }
            }
}

// ---------------------------------------------------------------------------
// 128x256 fused QKV GEMM (8-phase, MH=2): grid (24, 32). which = bx>>3.
// Q pre-scaled by log2(e)/sqrt(HD); V stored transposed.
__global__ __launch_bounds__(512, 1) void gemm_qkv128(
    const __bf16* __restrict__ A, const __bf16* __restrict__ Wall,
    __bf16* __restrict__ qout, __bf16* __restrict__ kout,
    __bf16* __restrict__ vtout) {
    constexpr int N = 2048, K = 2048;
    constexpr float kQScale = 1.4426950408889634f * 0.08838834764831845f;
    __shared__ __align__(16) __bf16 As[2][128][64];
    __shared__ __align__(16) __bf16 Bs[2][256][64];
    const int tid = threadIdx.x;
    const int wave = tid >> 6, lane = tid & 63;
    const int lr = lane & 15, lq = lane >> 4;
    const int wm = wave >> 2, wn = wave & 3;
    const int which = blockIdx.x >> 3;
    const int m0 = blockIdx.y * 128, n0 = (blockIdx.x & 7) * 256;
    const __bf16* W = Wall + (size_t)which * N * K;

    f32x4 acc[4][4];
    gemm_core_8ph<2>(A, W, m0, n0, K, &As[0][0][0], &Bs[0][0][0], acc);

    if (which < 2) {
        __bf16* outp = (which == 0) ? qout : kout;
        const float sc = (which == 0) ? kQScale : 1.0f;
#pragma unroll
        for (int m = 0; m < 4; ++m)
#pragma unroll
            for (int n = 0; n < 4; ++n)
#pragma unroll
                for (int r = 0; r < 4; ++r) {
                    int row = m0 + wm * 64 + m * 16 + lq * 4 + r;
                    int col = n0 + wn * 64 + n * 16 + lr;
                    outp[(size_t)row * N + col] = tobf(acc[m][n][r] * sc);
                }
    } else {
#pragma unroll
        for (int m = 0; m < 4; ++m)
#pragma unroll
            for (int n = 0; n < 4; ++n) {
                int t0 = m0 + wm * 64 + m * 16 + lq * 4;   // 4 consec tokens
                int b  = t0 >> 11, tt = t0 & 2047;
                int col = n0 + wn * 64 + n * 16 + lr;      // h*128 + d
                bf16x4 p = {tobf(acc[m][n][0]), tobf(acc[m][n][1]),
                            tobf(acc[m][n][2]), tobf(acc[m][n][3])};
                *(bf16x4*)(vtout + (((size_t)(b * 2048 + col)) << 11) + tt) = p;
            }
    }
}

// ---------------------------------------------------------------------------
// Causal flash attention (proven). Grid (16, H, B), block 256 (4 waves).
__global__ __launch_bounds__(256) void attn_kernel(
    const __bf16* __restrict__ Q, const __bf16* __restrict__ K,
    const __bf16* __restrict__ Vt, __bf16* __restrict__ O) {
    constexpr int T = 2048, C = 2048, HD = 128;
    __shared__ __align__(16) __bf16 Ks[64][136];
    __shared__ __align__(16) __bf16 Vts[128][72];
    __shared__ __align__(16) __bf16 Ps[4][16][72];
    const int t = threadIdx.x, w = t >> 6, lane = t & 63;
    const int lr = lane & 15, lq = lane >> 4;
    const int b = blockIdx.z, h = blockIdx.y;
    const __bf16* vtb = Vt + ((size_t)(b * 2048 + h * 128) << 11);
    const f32x4 zero = {0.f, 0.f, 0.f, 0.f};

    bf16x8 ones;
#pragma unroll
    for (int j = 0; j < 8; ++j) ones[j] = (lr == 0) ? (__bf16)1.0f : (__bf16)0.0f;

    for (int pass = 0; pass < 2; ++pass) {
        const int qblk = (pass == 0) ? blockIdx.x : 31 - blockIdx.x;
        const int q0 = qblk * 64;

        const int qrow = q0 + w * 16 + lr;
        const __bf16* qb = Q + (size_t)(b * T + qrow) * C + h * HD;
        bf16x8 qf[4];
#pragma unroll
        for (int s = 0; s < 4; ++s)
            qf[s] = *(const bf16x8*)(qb + s * 32 + lq * 8);

        f32x4 oacc[8], lacc = zero;
#pragma unroll
        for (int nc = 0; nc < 8; ++nc) oacc[nc] = zero;
        float m_i[4] = {-3e38f, -3e38f, -3e38f, -3e38f};

        for (int kb = 0; kb <= qblk; ++kb) {
            const int k00 = kb * 64;
#pragma unroll
            for (int i = 0; i < 4; ++i) {
                int c = t + 256 * i;
                int r = c >> 4, col = (c & 15) * 8;
                *(bf16x8*)&Ks[r][col] =
                    *(const bf16x8*)(K + (size_t)(b * T + k00 + r) * C + h * HD + col);
            }
#pragma unroll
            for (int i = 0; i < 4; ++i) {
                int c = t + 256 * i;
                int r = c >> 3, cg = (c & 7) * 8;
                *(bf16x8*)&Vts[r][cg] =
                    *(const bf16x8*)(vtb + ((size_t)r << 11) + k00 + cg);
            }
            __syncthreads();

            float pv[4][4];
#pragma unroll
            for (int jc = 0; jc < 4; ++jc) {
                f32x4 s = zero;
#pragma unroll
                for (int ks = 0; ks < 4; ++ks) {
                    bf16x8 kf = *(const bf16x8*)&Ks[jc * 16 + lr][ks * 32 + lq * 8];
                    s = __builtin_amdgcn_mfma_f32_16x16x32_bf16(qf[ks], kf, s, 0, 0, 0);
                }
#pragma unroll
                for (int r = 0; r < 4; ++r) pv[jc][r] = s[r];
            }
            if (kb == qblk) {
#pragma unroll
                for (int jc = 0; jc < 4; ++jc)
#pragma unroll
                    for (int r = 0; r < 4; ++r)
                        if (jc * 16 + lr > w * 16 + lq * 4 + r) pv[jc][r] = -3e38f;
            }
            float rmax[4];
#pragma unroll
            for (int r = 0; r < 4; ++r)
                rmax[r] = fmaxf(fmaxf(pv[0][r], pv[1][r]), fmaxf(pv[2][r], pv[3][r]));
#pragma unroll
            for (int off = 1; off < 16; off <<= 1)
#pragma unroll
                for (int r = 0; r < 4; ++r)
                    rmax[r] = fmaxf(rmax[r], __shfl_xor(rmax[r], off));
            float alpha[4];
#pragma unroll
            for (int r = 0; r < 4; ++r) {
                float mn = fmaxf(m_i[r], rmax[r]);
                alpha[r] = exp2f(m_i[r] - mn);
                m_i[r] = mn;
            }
#pragma unroll
            for (int jc = 0; jc < 4; ++jc)
#pragma unroll
                for (int r = 0; r < 4; ++r)
                    Ps[w][lq * 4 + r][jc * 16 + lr] = tobf(exp2f(pv[jc][r] - m_i[r]));
#pragma unroll
            for (int nc = 0; nc < 8; ++nc)
#pragma unroll
                for (int r = 0; r < 4; ++r) oacc[nc][r] *= alpha[r];
#pragma unroll
            for (int r = 0; r < 4; ++r) lacc[r] *= alpha[r];
            __syncthreads();

#pragma unroll
            for (int s2 = 0; s2 < 2; ++s2) {
                bf16x8 pa = *(const bf16x8*)&Ps[w][lr][s2 * 32 + lq * 8];
#pragma unroll
                for (int nc = 0; nc < 8; ++nc) {
                    bf16x8 vf = *(const bf16x8*)&Vts[nc * 16 + lr][s2 * 32 + lq * 8];
                    oacc[nc] = __builtin_amdgcn_mfma_f32_16x16x32_bf16(
                        pa, vf, oacc[nc], 0, 0, 0);
                }
                lacc = __builtin_amdgcn_mfma_f32_16x16x32_bf16(pa, ones, lacc, 0, 0, 0);
            }
            __syncthreads();
        }

        float inv[4];
#pragma unroll
        for (int r = 0; r < 4; ++r) inv[r] = 1.0f / __shfl(lacc[r], lane & 48);
#pragma unroll
        for (int nc = 0; nc < 8; ++nc)
#pragma unroll
            for (int r = 0; r < 4; ++r) {
                int row = q0 + w * 16 + lq * 4 + r;
                O[(size_t)(b * T + row) * C + h * HD + nc * 16 + lr] =
                    tobf(oacc[nc][r] * inv[r]);
            }
        __syncthreads();
    }
}

// ---------------------------------------------------------------------------
extern "C" void kernel_launch(void* const* d_in, const int* in_sizes, int n_in,
                              void* d_out, int out_size, void* d_ws, size_t ws_size,
                              hipStream_t stream) {
    const void* x   = d_in[0];
    const void* wq  = d_in[1];
    const void* wk  = d_in[2];
    const void* wv  = d_in[3];
    const void* wo  = d_in[4];
    const void* fc1 = d_in[5];
    const void* fc2 = d_in[6];
    constexpr int Bv = 2, Tv = 2048, Cv = 2048, Hv = 16, MLP = 8192;
    constexpr int M = Bv * Tv;                  // 4096 rows
    constexpr size_t NE = (size_t)M * Cv;       // 8,388,608
    constexpr size_t CC = (size_t)Cv * Cv;      // 4,194,304

    char* ws = (char*)d_ws;
    int*    flag = (int*)ws;                    // 256 B reserved
    __bf16* h    = (__bf16*)(ws + 256);         // NE bf16
    __bf16* qb   = h  + NE;                     // NE bf16
    __bf16* kb   = qb + NE;                     // NE bf16
    __bf16* vt   = kb + NE;                     // NE bf16 (V, pre-transposed)
    __bf16* ao   = vt + NE;                     // NE bf16
    float*  x1   = (float*)(ao + NE);           // NE fp32
    __bf16* mm   = (__bf16*)(x1 + NE);          // M*MLP bf16 (67.1 MB)
    // lifetime aliases:
    __bf16* wqkvob = mm;   // 4*CC bf16, dead before fc1 GEMM writes mm
    __bf16* fc1b   = qb;   // FCE bf16 = qb+kb, converted after attn
    __bf16* fc2b   = vt;   // FCE bf16 = vt+ao, converted after wo GEMM

    detect_dtype_kernel<<<1, 64, 0, stream>>>((const unsigned short*)x, flag);

    convert_w4<<<dim3(2048, 4), 256, 0, stream>>>(wq, wk, wv, wo, wqkvob, flag);

    rmsnorm_kernel<0><<<M, 256, 0, stream>>>(x, h, flag);

    // qkv (128x256 8-phase): 768 blocks = 3.0 rounds exactly
    gemm_qkv128<<<dim3(24, 32), 512, 0, stream>>>(h, wqkvob, qb, kb, vt);

    attn_kernel<<<dim3(16, Hv, Bv), 256, 0, stream>>>(qb, kb, vt, ao);

    // fc1 -> bf16 into qb+kb (dead after attn)
    convert_w1<<<8192, 256, 0, stream>>>(fc1, fc1b, flag);

    // wo (128x256 8-phase, 256 blocks): x1 = ao @ wo^T + x
    gemm128_nt<5><<<dim3(8, 32), 512, 0, stream>>>(ao, wqkvob + 3 * CC, x1, x,
                                                   M, Cv, Cv, flag);

    // fc2 -> bf16 into vt+ao (dead after wo GEMM)
    convert_w1<<<8192, 256, 0, stream>>>(fc2, fc2b, flag);

    rmsnorm_kernel<1><<<M, 256, 0, stream>>>(x1, h, flag);

    // fc1 (256^2 8-phase, 512 blocks = 2.0 rounds): mm = relu(h @ fc1^T)^2
    gemm256_nt<2><<<dim3(32, 16), 512, 0, stream>>>(h, fc1b, mm, nullptr,
                                                    M, MLP, Cv, flag);

    // fc2 (128x256 8-phase, 256 blocks): d_out = mm @ fc2^T + x1
    gemm128_nt<6><<<dim3(8, 32), 512, 0, stream>>>(mm, fc2b, d_out, x1,
                                                   M, Cv, MLP, flag);
}

// Round 7
// 772.390 us; speedup vs baseline: 1.0684x; 1.0684x over previous
//
#include <hip/hip_runtime.h>

// ---------------------------------------------------------------------------
// TransformerBlock: B=2 T=2048 C=2048 H=16 HD=128 MLP=8192, causal, relu^2 MLP
// Round 11 = Round 10 with the prefetch core FIXED:
//  (a) last K-tile drains vmcnt(0) (R10 bug: vmcnt(8) was a no-op when no new
//      stage was issued -> MFMA could read un-landed LDS);
//  (b) compiler-only memory fences around raw s_barrier (LLVM s_barrier is
//      IntrNoMem -> without them, staging could hoist above the trailing
//      barrier into the buffer other waves still read). NOT sched_barrier.
//  - fc1: 256^2 8-phase (validated R4/R5, byte-identical to R4).
//  - qkv/wo/fc2: prefetch double-buffered 2-phase 128^2 core: stage t+1
//    BEFORE compute t, raw s_barrier, counted vmcnt(8) -> no per-tile drain.
//
// mfma_f32_16x16x32_bf16 layouts (learn_hip m89/m91):
//   A[m=lane&15][k=(lane>>4)*8+j], B[n=lane&15][k=(lane>>4)*8+j]
//   D[row=(lane>>4)*4+reg][col=lane&15]
//
// Workspace (184.5 MB, proven):
//   flag(256B) | h | qb | kb | vt | ao | x1(f32) | mm(2*FCE bf16)
// Aliases: wqkvo_b=mm (dead until fc1 GEMM), fc1b=qb..kb (after attn),
//          fc2b=vt..ao (after wo GEMM).
// ---------------------------------------------------------------------------

typedef __bf16 bf16x8 __attribute__((ext_vector_type(8)));
typedef __bf16 bf16x4 __attribute__((ext_vector_type(4)));
typedef float  f32x4  __attribute__((ext_vector_type(4)));

static __device__ __forceinline__ __bf16 tobf(float f) { return (__bf16)f; }

// async 16B global->LDS; lptr wave-uniform, HW writes lane l at lptr + l*16.
static __device__ __forceinline__ void async_copy16(const void* g, void* l) {
    __builtin_amdgcn_global_load_lds(
        (const __attribute__((address_space(1))) void*)g,
        (__attribute__((address_space(3))) void*)l, 16, 0, 0);
}

// memory-clobber pins memory ops to their phase; register-only MFMA stays
// schedulable (R3->R4 lesson: NO sched_barrier here).
#define LGKM0_FENCE()  asm volatile("s_waitcnt lgkmcnt(0)" ::: "memory")
#define VMCNT8_FENCE() asm volatile("s_waitcnt vmcnt(8)" ::: "memory")
#define VMCNT0_FENCE() asm volatile("s_waitcnt vmcnt(0)" ::: "memory")
// compiler-only fence: blocks LLVM memory-op motion, emits no instruction.
#define CFENCE()       asm volatile("" ::: "memory")

// ---------------------------------------------------------------------------
__global__ void detect_dtype_kernel(const unsigned short* __restrict__ xh,
                                    int* __restrict__ flag) {
    int t = threadIdx.x;                       // one wave of 64
    unsigned short u = xh[2 * t];              // even ushort slots
    int e = (u >> 7) & 0xFF;                   // bf16 exponent field
    bool outlier = (e < 100) || (e > 131);     // implausible for N(0,1)
    unsigned long long m = __ballot(outlier);
    if (t == 0) *flag = (__popcll(m) >= 16) ? 1 : 0;   // 1 => fp32 buffers
}

// ---------------------------------------------------------------------------
// Weight conversion, 8 elems/thread.
__global__ __launch_bounds__(256) void convert_w4(
    const void* __restrict__ w0, const void* __restrict__ w1,
    const void* __restrict__ w2, const void* __restrict__ w3,
    __bf16* __restrict__ dqkvo, const int* __restrict__ flagp) {
    constexpr size_t CC = (size_t)2048 * 2048;
    const int y = blockIdx.y;
    size_t i = ((size_t)blockIdx.x * 256 + threadIdx.x) * 8;
    const void* s = (y == 0) ? w0 : (y == 1) ? w1 : (y == 2) ? w2 : w3;
    __bf16* d = dqkvo + (size_t)y * CC;
    if (*flagp != 0) {
        const float4* sp = (const float4*)((const float*)s + i);
        float4 a = sp[0], b = sp[1];
        bf16x8 o = {tobf(a.x), tobf(a.y), tobf(a.z), tobf(a.w),
                    tobf(b.x), tobf(b.y), tobf(b.z), tobf(b.w)};
        *(bf16x8*)(d + i) = o;
    } else {
        *(bf16x8*)(d + i) = *(const bf16x8*)((const __bf16*)s + i);
    }
}

__global__ __launch_bounds__(256) void convert_w1(
    const void* __restrict__ src, __bf16* __restrict__ dst,
    const int* __restrict__ flagp) {
    size_t i = ((size_t)blockIdx.x * 256 + threadIdx.x) * 8;
    if (*flagp != 0) {
        const float4* sp = (const float4*)((const float*)src + i);
        float4 a = sp[0], b = sp[1];
        bf16x8 o = {tobf(a.x), tobf(a.y), tobf(a.z), tobf(a.w),
                    tobf(b.x), tobf(b.y), tobf(b.z), tobf(b.w)};
        *(bf16x8*)(dst + i) = o;
    } else {
        *(bf16x8*)(dst + i) = *(const bf16x8*)((const __bf16*)src + i);
    }
}

// ---------------------------------------------------------------------------
// rmsnorm: row of C=2048, one block per row, 256 threads x 8 elements.
template <int SRC>
__global__ __launch_bounds__(256) void rmsnorm_kernel(
    const void* __restrict__ xp, __bf16* __restrict__ h,
    const int* __restrict__ flagp) {
    constexpr int C = 2048;
    const int row = blockIdx.x, t = threadIdx.x;
    float vals[8];
    bool f32in = (SRC == 1) || (*flagp != 0);
    if (f32in) {
        const float4* xr = (const float4*)((const float*)xp + (size_t)row * C);
        float4 a = xr[2 * t], b = xr[2 * t + 1];
        vals[0] = a.x; vals[1] = a.y; vals[2] = a.z; vals[3] = a.w;
        vals[4] = b.x; vals[5] = b.y; vals[6] = b.z; vals[7] = b.w;
    } else {
        bf16x8 a = *((const bf16x8*)((const __bf16*)xp + (size_t)row * C) + t);
#pragma unroll
        for (int j = 0; j < 8; ++j) vals[j] = (float)a[j];
    }
    float ss = 0.f;
#pragma unroll
    for (int j = 0; j < 8; ++j) ss += vals[j] * vals[j];
#pragma unroll
    for (int off = 32; off > 0; off >>= 1) ss += __shfl_down(ss, off);
    __shared__ float red[4];
    if ((t & 63) == 0) red[t >> 6] = ss;
    __syncthreads();
    float mean = (red[0] + red[1] + red[2] + red[3]) * (1.0f / C);
    float sc = rsqrtf(mean + 1e-5f);
    bf16x8 o;
#pragma unroll
    for (int j = 0; j < 8; ++j) o[j] = tobf(vals[j] * sc);
    *((bf16x8*)(h + (size_t)row * C) + t) = o;
}

// ---------------------------------------------------------------------------
// Prefetch double-buffered 128x128 2-phase core (T3 minimum recipe), FIXED.
// BK=64, 4 waves. XOR slot swizzle (phys slot = logical ^ (row&7)); dest
// linear, source pre-swizzled, reads swizzled (0 conflicts, proven R2).
// Per K-tile: {stage t+1 -> buf^1 ; vmcnt(8)} or {vmcnt(0) on last tile};
// s_barrier ; ds_read+MFMA ; s_barrier. Next tile's loads stay in flight
// across both barriers; HBM latency hides under the 32-MFMA cluster.
// Hazards: RAW mid-loop — vmcnt(8) leaves exactly tile(t+1)'s 8 loads
// outstanding, so tile t landed (oldest-first). RAW last tile — vmcnt(0)
// drains. WAR — iter t+1's stage overwrites the buffer read in iter t only
// after iter t's trailing barrier; CFENCE() stops compiler hoisting the
// async stage above that barrier (s_barrier intrinsic is IntrNoMem).
static __device__ __forceinline__ void gemm_core_128pf(
    const __bf16* __restrict__ A, const __bf16* __restrict__ W,
    int m0, int n0, int K,
    __bf16 (*As)[128][64], __bf16 (*Bs)[128][64], f32x4 (&acc)[4][4]) {
    const int t = threadIdx.x;
    const int wave = t >> 6, lane = t & 63;
    const int lr = lane & 15, lq = lane >> 4;
    const int wm = wave & 1, wn = wave >> 1;
    const int sx = lr & 7;
    const int NT = K >> 6;

    const __bf16* gA[4];
    const __bf16* gB[4];
    int lo[4];
#pragma unroll
    for (int i = 0; i < 4; ++i) {
        int c = i * 256 + t;
        int row = c >> 3;
        int sl = (c & 7) ^ (row & 7);
        gA[i] = A + (size_t)(m0 + row) * K + sl * 8;
        gB[i] = W + (size_t)(n0 + row) * K + sl * 8;
        lo[i] = (c & ~63) * 8;
    }

    const f32x4 zero = {0.f, 0.f, 0.f, 0.f};
#pragma unroll
    for (int i = 0; i < 4; ++i)
#pragma unroll
        for (int j = 0; j < 4; ++j) acc[i][j] = zero;

    // prologue: stage tile 0 -> buf 0
#pragma unroll
    for (int i = 0; i < 4; ++i) {
        async_copy16(gA[i], &As[0][0][0] + lo[i]);
        async_copy16(gB[i], &Bs[0][0][0] + lo[i]);
    }

    for (int tt = 0; tt < NT; ++tt) {
        const int cur = tt & 1;
        if (tt + 1 < NT) {                       // block-uniform branch
            const int k1 = (tt + 1) * 64;
#pragma unroll
            for (int i = 0; i < 4; ++i) {
                async_copy16(gA[i] + k1, &As[cur ^ 1][0][0] + lo[i]);
                async_copy16(gB[i] + k1, &Bs[cur ^ 1][0][0] + lo[i]);
            }
            VMCNT8_FENCE();                      // tile tt landed (8 newest ok)
        } else {
            VMCNT0_FENCE();                      // FIX: drain final tile
        }
        __builtin_amdgcn_s_barrier();            // ... and chip-wide
        CFENCE();                                // reads stay below barrier

        bf16x8 a[4][2], b[4][2];
#pragma unroll
        for (int kk = 0; kk < 2; ++kk) {
            const int sp = ((kk * 4 + lq) ^ sx) * 8;
#pragma unroll
            for (int ii = 0; ii < 4; ++ii) {
                a[ii][kk] = *(const bf16x8*)&As[cur][wm * 64 + ii * 16 + lr][sp];
                b[ii][kk] = *(const bf16x8*)&Bs[cur][wn * 64 + ii * 16 + lr][sp];
            }
        }
#pragma unroll
        for (int ii = 0; ii < 4; ++ii)
#pragma unroll
            for (int jj = 0; jj < 4; ++jj)
#pragma unroll
                for (int kk = 0; kk < 2; ++kk)
                    acc[ii][jj] = __builtin_amdgcn_mfma_f32_16x16x32_bf16(
                        a[ii][kk], b[jj][kk], acc[ii][jj], 0, 0, 0);
        CFENCE();                                // reads stay above barrier
        __builtin_amdgcn_s_barrier();            // reads done before overwrite
        CFENCE();                                // next stage stays below
    }
}

// 128^2 prefetch NT GEMM. EPI 5: fp32 out=acc+res (wo);
// EPI 6: out=acc+res_f32, out dtype per flag (fc2).
template <int EPI>
__global__ __launch_bounds__(256) void gemm_nt(
    const __bf16* __restrict__ A, const __bf16* __restrict__ W,
    void* __restrict__ outp, const void* __restrict__ resp,
    int M, int N, int K, const int* __restrict__ flagp) {
    __shared__ __align__(16) __bf16 As[2][128][64];
    __shared__ __align__(16) __bf16 Bs[2][128][64];
    const int t = threadIdx.x;
    const int wave = t >> 6, lane = t & 63;
    const int lr = lane & 15, lq = lane >> 4;
    const int wm = wave & 1, wn = wave >> 1;
    const int m0 = blockIdx.y * 128, n0 = blockIdx.x * 128;

    f32x4 acc[4][4];
    gemm_core_128pf(A, W, m0, n0, K, As, Bs, acc);

    const bool f32 = (*flagp != 0);
#pragma unroll
    for (int i = 0; i < 4; ++i)
#pragma unroll
        for (int j = 0; j < 4; ++j)
#pragma unroll
            for (int r = 0; r < 4; ++r) {
                int row = m0 + wm * 64 + i * 16 + lq * 4 + r;
                int col = n0 + wn * 64 + j * 16 + lr;
                size_t o = (size_t)row * N + col;
                float v = acc[i][j][r];
                if (EPI == 5) {
                    float res = f32 ? ((const float*)resp)[o]
                                    : (float)((const __bf16*)resp)[o];
                    ((float*)outp)[o] = v + res;
                } else {  // EPI 6
                    float ov = v + ((const float*)resp)[o];
                    if (f32) ((float*)outp)[o] = ov;
                    else     ((__bf16*)outp)[o] = tobf(ov);
                }
            }
}

// ---------------------------------------------------------------------------
// Fused QKV GEMM on the prefetch 128^2 core: grid (48, 32), 1536 blocks =
// 6.0 perfect dispatch rounds. which = bx>>4 selects weight/output.
// Q pre-scaled by log2(e)/sqrt(HD); V stored transposed.
__global__ __launch_bounds__(256) void gemm_qkv(
    const __bf16* __restrict__ A, const __bf16* __restrict__ Wall,
    __bf16* __restrict__ qout, __bf16* __restrict__ kout,
    __bf16* __restrict__ vtout) {
    constexpr int N = 2048, K = 2048;
    constexpr float kQScale = 1.4426950408889634f * 0.08838834764831845f;
    __shared__ __align__(16) __bf16 As[2][128][64];
    __shared__ __align__(16) __bf16 Bs[2][128][64];
    const int t = threadIdx.x;
    const int wave = t >> 6, lane = t & 63;
    const int lr = lane & 15, lq = lane >> 4;
    const int wm = wave & 1, wn = wave >> 1;
    const int which = blockIdx.x >> 4;
    const int m0 = blockIdx.y * 128, n0 = (blockIdx.x & 15) * 128;
    const __bf16* W = Wall + (size_t)which * N * K;

    f32x4 acc[4][4];
    gemm_core_128pf(A, W, m0, n0, K, As, Bs, acc);

    if (which < 2) {
        __bf16* outp = (which == 0) ? qout : kout;
        const float sc = (which == 0) ? kQScale : 1.0f;
#pragma unroll
        for (int i = 0; i < 4; ++i)
#pragma unroll
            for (int j = 0; j < 4; ++j)
#pragma unroll
                for (int r = 0; r < 4; ++r) {
                    int row = m0 + wm * 64 + i * 16 + lq * 4 + r;
                    int col = n0 + wn * 64 + j * 16 + lr;
                    outp[(size_t)row * N + col] = tobf(acc[i][j][r] * sc);
                }
    } else {
#pragma unroll
        for (int i = 0; i < 4; ++i)
#pragma unroll
            for (int j = 0; j < 4; ++j) {
                int t0 = m0 + wm * 64 + i * 16 + lq * 4;   // 4 consec tokens
                int b  = t0 >> 11, tt = t0 & 2047;
                int col = n0 + wn * 64 + j * 16 + lr;      // h*128 + d
                bf16x4 p = {tobf(acc[i][j][0]), tobf(acc[i][j][1]),
                            tobf(acc[i][j][2]), tobf(acc[i][j][3])};
                *(bf16x4*)(vtout + (((size_t)(b * 2048 + col)) << 11) + tt) = p;
            }
    }
}

// ---------------------------------------------------------------------------
// 256x256 8-phase core (validated R4/R5, UNCHANGED). 512 threads = 8 waves.
static __device__ __forceinline__ void gemm_core_256(
    const __bf16* __restrict__ A, const __bf16* __restrict__ W,
    int m0, int n0, int K,
    __bf16 (*As)[256][64], __bf16 (*Bs)[256][64], f32x4 (&acc)[8][4]) {
    const int tid = threadIdx.x;
    const int wave = tid >> 6, lane = tid & 63;
    const int lr = lane & 15, lq = lane >> 4;
    const int wm = wave >> 2, wn = wave & 3;
    const int sx = lr & 7;
    const int NT = K >> 6;

    int off[4], lo[4];
#pragma unroll
    for (int i = 0; i < 4; ++i) {
        int c = i * 512 + tid;
        int row = c >> 3;
        off[i] = row * K + (((c & 7) ^ (row & 7)) * 8);
        lo[i] = (c & ~63) * 8;
    }

    const f32x4 zero = {0.f, 0.f, 0.f, 0.f};
#pragma unroll
    for (int m = 0; m < 8; ++m)
#pragma unroll
        for (int n = 0; n < 4; ++n) acc[m][n] = zero;

#pragma unroll
    for (int pt = 0; pt < 2; ++pt) {
        const __bf16* ga = A + (size_t)m0 * K + pt * 64;
        const __bf16* gb = W + (size_t)n0 * K + pt * 64;
#pragma unroll
        for (int i = 0; i < 4; ++i)
            async_copy16(ga + off[i], &As[pt][0][0] + lo[i]);
#pragma unroll
        for (int i = 0; i < 4; ++i)
            async_copy16(gb + off[i], &Bs[pt][0][0] + lo[i]);
    }
    VMCNT8_FENCE();
    __builtin_amdgcn_s_barrier();

    for (int t = 0; t < NT; ++t) {
        const int bi = t & 1;
        const __bf16 (*Ac)[64] = As[bi];
        const __bf16 (*Bc)[64] = Bs[bi];
        const int ts = (t + 2 < NT) ? t + 2 : NT - 1;   // clamp: safe dummy
        const __bf16* gAt = A + (size_t)m0 * K + (size_t)ts * 64;
        const __bf16* gBt = W + (size_t)n0 * K + (size_t)ts * 64;

        bf16x8 a0[4][2], a1[4][2], b0[2][2], b1[2][2];

        // ---- Q0: read a0 (m0-3) + b0 (n0-1); mfma a0 x b0 ----
#pragma unroll
        for (int m = 0; m < 4; ++m)
#pragma unroll
            for (int kk = 0; kk < 2; ++kk)
                a0[m][kk] = *(const bf16x8*)
                    &Ac[wm * 128 + m * 16 + lr][((kk * 4 + lq) ^ sx) * 8];
#pragma unroll
        for (int n = 0; n < 2; ++n)
#pragma unroll
            for (int kk = 0; kk < 2; ++kk)
                b0[n][kk] = *(const bf16x8*)
                    &Bc[wn * 64 + n * 16 + lr][((kk * 4 + lq) ^ sx) * 8];
        __builtin_amdgcn_s_barrier();
        LGKM0_FENCE();
        __builtin_amdgcn_s_setprio(1);
#pragma unroll
        for (int m = 0; m < 4; ++m)
#pragma unroll
            for (int n = 0; n < 2; ++n)
#pragma unroll
                for (int kk = 0; kk < 2; ++kk)
                    acc[m][n] = __builtin_amdgcn_mfma_f32_16x16x32_bf16(
                        a0[m][kk], b0[n][kk], acc[m][n], 0, 0, 0);
        __builtin_amdgcn_s_setprio(0);
        __builtin_amdgcn_s_barrier();

        // ---- Q1: read a1 (m4-7); mfma a1 x b0 ----
#pragma unroll
        for (int m = 0; m < 4; ++m)
#pragma unroll
            for (int kk = 0; kk < 2; ++kk)
                a1[m][kk] = *(const bf16x8*)
                    &Ac[wm * 128 + (m + 4) * 16 + lr][((kk * 4 + lq) ^ sx) * 8];
        __builtin_amdgcn_s_barrier();
        LGKM0_FENCE();
        __builtin_amdgcn_s_setprio(1);
#pragma unroll
        for (int m = 0; m < 4; ++m)
#pragma unroll
            for (int n = 0; n < 2; ++n)
#pragma unroll
                for (int kk = 0; kk < 2; ++kk)
                    acc[m + 4][n] = __builtin_amdgcn_mfma_f32_16x16x32_bf16(
                        a1[m][kk], b0[n][kk], acc[m + 4][n], 0, 0, 0);
        __builtin_amdgcn_s_setprio(0);
        __builtin_amdgcn_s_barrier();
        // (A rows of tile t ds_read-complete chip-wide here)

        // ---- Q2: read b1 (n2-3); stage A(t+2)->bi; mfma a1 x b1 ----
#pragma unroll
        for (int n = 0; n < 2; ++n)
#pragma unroll
            for (int kk = 0; kk < 2; ++kk)
                b1[n][kk] = *(const bf16x8*)
                    &Bc[wn * 64 + (n + 2) * 16 + lr][((kk * 4 + lq) ^ sx) * 8];
#pragma unroll
        for (int i = 0; i < 4; ++i)
            async_copy16(gAt + off[i], &As[bi][0][0] + lo[i]);
        __builtin_amdgcn_s_barrier();
        LGKM0_FENCE();
        __builtin_amdgcn_s_setprio(1);
#pragma unroll
        for (int m = 0; m < 4; ++m)
#pragma unroll
            for (int n = 0; n < 2; ++n)
#pragma unroll
                for (int kk = 0; kk < 2; ++kk)
                    acc[m + 4][n + 2] = __builtin_amdgcn_mfma_f32_16x16x32_bf16(
                        a1[m][kk], b1[n][kk], acc[m + 4][n + 2], 0, 0, 0);
        __builtin_amdgcn_s_setprio(0);
        __builtin_amdgcn_s_barrier();
        // (B rows of tile t ds_read-complete chip-wide here)

        // ---- Q3: stage B(t+2)->bi; mfma a0 x b1; counted vmcnt ----
#pragma unroll
        for (int i = 0; i < 4; ++i)
            async_copy16(gBt + off[i], &Bs[bi][0][0] + lo[i]);
        __builtin_amdgcn_s_barrier();
        __builtin_amdgcn_s_setprio(1);
#pragma unroll
        for (int m = 0; m < 4; ++m)
#pragma unroll
            for (int n = 0; n < 2; ++n)
#pragma unroll
                for (int kk = 0; kk < 2; ++kk)
                    acc[m][n + 2] = __builtin_amdgcn_mfma_f32_16x16x32_bf16(
                        a0[m][kk], b1[n][kk], acc[m][n + 2], 0, 0, 0);
        __builtin_amdgcn_s_setprio(0);
        VMCNT8_FENCE();   // tile t+1 fully landed; t+2's 8 loads stay in flight
        __builtin_amdgcn_s_barrier();
    }
}

// 256^2 NT GEMM (8-phase). EPI 2: bf16 relu(acc)^2 (fc1).
template <int EPI>
__global__ __launch_bounds__(512, 1) void gemm256_nt(
    const __bf16* __restrict__ A, const __bf16* __restrict__ W,
    void* __restrict__ outp, const void* __restrict__ resp,
    int M, int N, int K, const int* __restrict__ flagp) {
    __shared__ __align__(16) __bf16 As[2][256][64];
    __shared__ __align__(16) __bf16 Bs[2][256][64];
    const int tid = threadIdx.x;
    const int wave = tid >> 6, lane = tid & 63;
    const int lr = lane & 15, lq = lane >> 4;
    const int wm = wave >> 2, wn = wave & 3;
    const int m0 = blockIdx.y * 256, n0 = blockIdx.x * 256;

    f32x4 acc[8][4];
    gemm_core_256(A, W, m0, n0, K, As, Bs, acc);

    const bool f32 = (EPI == 2) ? false : (*flagp != 0);
#pragma unroll
    for (int m = 0; m < 8; ++m)
#pragma unroll
        for (int n = 0; n < 4; ++n)
#pragma unroll
            for (int r = 0; r < 4; ++r) {
                int row = m0 + wm * 128 + m * 16 + lq * 4 + r;
                int col = n0 + wn * 64 + n * 16 + lr;
                size_t o = (size_t)row * N + col;
                float v = acc[m][n][r];
                if (EPI == 2) {
                    float rv = v > 0.f ? v : 0.f;
                    ((__bf16*)outp)[o] = tobf(rv * rv);
                } else if (EPI == 5) {
                    float res = f32 ? ((const float*)resp)[o]
                                    : (float)((const __bf16*)resp)[o];
                    ((float*)outp)[o] = v + res;
                } else {  // EPI 6
                    float ov = v + ((const float*)resp)[o];
                    if (f32) ((float*)outp)[o] = ov;
                    else     ((__bf16*)outp)[o] = tobf(ov);
                }
            }
}

// ---------------------------------------------------------------------------
// Causal flash attention (proven). Grid (16, H, B), block 256 (4 waves).
__global__ __launch_bounds__(256) void attn_kernel(
    const __bf16* __restrict__ Q, const __bf16* __restrict__ K,
    const __bf16* __restrict__ Vt, __bf16* __restrict__ O) {
    constexpr int T = 2048, C = 2048, HD = 128;
    __shared__ __align__(16) __bf16 Ks[64][136];
    __shared__ __align__(16) __bf16 Vts[128][72];
    __shared__ __align__(16) __bf16 Ps[4][16][72];
    const int t = threadIdx.x, w = t >> 6, lane = t & 63;
    const int lr = lane & 15, lq = lane >> 4;
    const int b = blockIdx.z, h = blockIdx.y;
    const __bf16* vtb = Vt + ((size_t)(b * 2048 + h * 128) << 11);
    const f32x4 zero = {0.f, 0.f, 0.f, 0.f};

    bf16x8 ones;
#pragma unroll
    for (int j = 0; j < 8; ++j) ones[j] = (lr == 0) ? (__bf16)1.0f : (__bf16)0.0f;

    for (int pass = 0; pass < 2; ++pass) {
        const int qblk = (pass == 0) ? blockIdx.x : 31 - blockIdx.x;
        const int q0 = qblk * 64;

        const int qrow = q0 + w * 16 + lr;
        const __bf16* qb = Q + (size_t)(b * T + qrow) * C + h * HD;
        bf16x8 qf[4];
#pragma unroll
        for (int s = 0; s < 4; ++s)
            qf[s] = *(const bf16x8*)(qb + s * 32 + lq * 8);

        f32x4 oacc[8], lacc = zero;
#pragma unroll
        for (int nc = 0; nc < 8; ++nc) oacc[nc] = zero;
        float m_i[4] = {-3e38f, -3e38f, -3e38f, -3e38f};

        for (int kb = 0; kb <= qblk; ++kb) {
            const int k00 = kb * 64;
#pragma unroll
            for (int i = 0; i < 4; ++i) {
                int c = t + 256 * i;
                int r = c >> 4, col = (c & 15) * 8;
                *(bf16x8*)&Ks[r][col] =
                    *(const bf16x8*)(K + (size_t)(b * T + k00 + r) * C + h * HD + col);
            }
#pragma unroll
            for (int i = 0; i < 4; ++i) {
                int c = t + 256 * i;
                int r = c >> 3, cg = (c & 7) * 8;
                *(bf16x8*)&Vts[r][cg] =
                    *(const bf16x8*)(vtb + ((size_t)r << 11) + k00 + cg);
            }
            __syncthreads();

            float pv[4][4];
#pragma unroll
            for (int jc = 0; jc < 4; ++jc) {
                f32x4 s = zero;
#pragma unroll
                for (int ks = 0; ks < 4; ++ks) {
                    bf16x8 kf = *(const bf16x8*)&Ks[jc * 16 + lr][ks * 32 + lq * 8];
                    s = __builtin_amdgcn_mfma_f32_16x16x32_bf16(qf[ks], kf, s, 0, 0, 0);
                }
#pragma unroll
                for (int r = 0; r < 4; ++r) pv[jc][r] = s[r];
            }
            if (kb == qblk) {
#pragma unroll
                for (int jc = 0; jc < 4; ++jc)
#pragma unroll
                    for (int r = 0; r < 4; ++r)
                        if (jc * 16 + lr > w * 16 + lq * 4 + r) pv[jc][r] = -3e38f;
            }
            float rmax[4];
#pragma unroll
            for (int r = 0; r < 4; ++r)
                rmax[r] = fmaxf(fmaxf(pv[0][r], pv[1][r]), fmaxf(pv[2][r], pv[3][r]));
#pragma unroll
            for (int off = 1; off < 16; off <<= 1)
#pragma unroll
                for (int r = 0; r < 4; ++r)
                    rmax[r] = fmaxf(rmax[r], __shfl_xor(rmax[r], off));
            float alpha[4];
#pragma unroll
            for (int r = 0; r < 4; ++r) {
                float mn = fmaxf(m_i[r], rmax[r]);
                alpha[r] = exp2f(m_i[r] - mn);
                m_i[r] = mn;
            }
#pragma unroll
            for (int jc = 0; jc < 4; ++jc)
#pragma unroll
                for (int r = 0; r < 4; ++r)
                    Ps[w][lq * 4 + r][jc * 16 + lr] = tobf(exp2f(pv[jc][r] - m_i[r]));
#pragma unroll
            for (int nc = 0; nc < 8; ++nc)
#pragma unroll
                for (int r = 0; r < 4; ++r) oacc[nc][r] *= alpha[r];
#pragma unroll
            for (int r = 0; r < 4; ++r) lacc[r] *= alpha[r];
            __syncthreads();

#pragma unroll
            for (int s2 = 0; s2 < 2; ++s2) {
                bf16x8 pa = *(const bf16x8*)&Ps[w][lr][s2 * 32 + lq * 8];
#pragma unroll
                for (int nc = 0; nc < 8; ++nc) {
                    bf16x8 vf = *(const bf16x8*)&Vts[nc * 16 + lr][s2 * 32 + lq * 8];
                    oacc[nc] = __builtin_amdgcn_mfma_f32_16x16x32_bf16(
                        pa, vf, oacc[nc], 0, 0, 0);
                }
                lacc = __builtin_amdgcn_mfma_f32_16x16x32_bf16(pa, ones, lacc, 0, 0, 0);
            }
            __syncthreads();
        }

        float inv[4];
#pragma unroll
        for (int r = 0; r < 4; ++r) inv[r] = 1.0f / __shfl(lacc[r], lane & 48);
#pragma unroll
        for (int nc = 0; nc < 8; ++nc)
#pragma unroll
            for (int r = 0; r < 4; ++r) {
                int row = q0 + w * 16 + lq * 4 + r;
                O[(size_t)(b * T + row) * C + h * HD + nc * 16 + lr] =
                    tobf(oacc[nc][r] * inv[r]);
            }
        __syncthreads();
    }
}

// ---------------------------------------------------------------------------
extern "C" void kernel_launch(void* const* d_in, const int* in_sizes, int n_in,
                              void* d_out, int out_size, void* d_ws, size_t ws_size,
                              hipStream_t stream) {
    const void* x   = d_in[0];
    const void* wq  = d_in[1];
    const void* wk  = d_in[2];
    const void* wv  = d_in[3];
    const void* wo  = d_in[4];
    const void* fc1 = d_in[5];
    const void* fc2 = d_in[6];
    constexpr int Bv = 2, Tv = 2048, Cv = 2048, Hv = 16, MLP = 8192;
    constexpr int M = Bv * Tv;                  // 4096 rows
    constexpr size_t NE = (size_t)M * Cv;       // 8,388,608
    constexpr size_t CC = (size_t)Cv * Cv;      // 4,194,304

    char* ws = (char*)d_ws;
    int*    flag = (int*)ws;                    // 256 B reserved
    __bf16* h    = (__bf16*)(ws + 256);         // NE bf16
    __bf16* qb   = h  + NE;                     // NE bf16
    __bf16* kb   = qb + NE;                     // NE bf16
    __bf16* vt   = kb + NE;                     // NE bf16 (V, pre-transposed)
    __bf16* ao   = vt + NE;                     // NE bf16
    float*  x1   = (float*)(ao + NE);           // NE fp32
    __bf16* mm   = (__bf16*)(x1 + NE);          // M*MLP bf16 (67.1 MB)
    // lifetime aliases:
    __bf16* wqkvob = mm;   // 4*CC bf16, dead before fc1 GEMM writes mm
    __bf16* fc1b   = qb;   // FCE bf16 = qb+kb, converted after attn
    __bf16* fc2b   = vt;   // FCE bf16 = vt+ao, converted after wo GEMM

    detect_dtype_kernel<<<1, 64, 0, stream>>>((const unsigned short*)x, flag);

    convert_w4<<<dim3(2048, 4), 256, 0, stream>>>(wq, wk, wv, wo, wqkvob, flag);

    rmsnorm_kernel<0><<<M, 256, 0, stream>>>(x, h, flag);

    // qkv (prefetch 128^2): 1536 blocks = 6.0 perfect rounds
    gemm_qkv<<<dim3(48, 32), 256, 0, stream>>>(h, wqkvob, qb, kb, vt);

    attn_kernel<<<dim3(16, Hv, Bv), 256, 0, stream>>>(qb, kb, vt, ao);

    // fc1 -> bf16 into qb+kb (dead after attn)
    convert_w1<<<8192, 256, 0, stream>>>(fc1, fc1b, flag);

    // wo (prefetch 128^2, 512 blocks): x1 = ao @ wo^T + x
    gemm_nt<5><<<dim3(16, 32), 256, 0, stream>>>(ao, wqkvob + 3 * CC, x1, x,
                                                 M, Cv, Cv, flag);

    // fc2 -> bf16 into vt+ao (dead after wo GEMM)
    convert_w1<<<8192, 256, 0, stream>>>(fc2, fc2b, flag);

    rmsnorm_kernel<1><<<M, 256, 0, stream>>>(x1, h, flag);

    // fc1 (256^2 8-phase, 512 blocks = 2.0 rounds): mm = relu(h @ fc1^T)^2
    gemm256_nt<2><<<dim3(32, 16), 512, 0, stream>>>(h, fc1b, mm, nullptr,
                                                    M, MLP, Cv, flag);

    // fc2 (prefetch 128^2, 512 blocks): d_out = mm @ fc2^T + x1
    gemm_nt<6><<<dim3(16, 32), 256, 0, stream>>>(mm, fc2b, d_out, x1,
                                                 M, Cv, MLP, flag);
}

// Round 8
// 757.619 us; speedup vs baseline: 1.0892x; 1.0195x over previous
//
#include <hip/hip_runtime.h>

// ---------------------------------------------------------------------------
// TransformerBlock: B=2 T=2048 C=2048 H=16 HD=128 MLP=8192, causal, relu^2 MLP
// Round 12 = Round 11 + three independent low-risk levers:
//  (1) prefetch core: kk-interleaved compute (read kk0 / mfma kk0 / read kk1 /
//      mfma kk1) — halves the front-loaded LDS burst, lets MFMA overlap reads;
//  (2) wo/fc2: m204-bijective XCD swizzle — each XCD owns a contiguous run of
//      64 tiles (4 A-panels), live K-slices stay L2-resident -> prefetch hits
//      L2 (~200cy) not HBM (~900cy). FETCH 297MB vs 134 ideal was the smell.
//  (3) attn: T14 async-stage split — kb+1's K/V global loads issue right
//      after kb's LDS writes; HBM latency hides under QK+softmax+PV.
//  - fc1: 256^2 8-phase (validated, unchanged). qkv: prefetch 128^2 unchanged.
//
// mfma_f32_16x16x32_bf16 layouts (learn_hip m89/m91):
//   A[m=lane&15][k=(lane>>4)*8+j], B[n=lane&15][k=(lane>>4)*8+j]
//   D[row=(lane>>4)*4+reg][col=lane&15]
//
// Workspace (184.5 MB, proven):
//   flag(256B) | h | qb | kb | vt | ao | x1(f32) | mm(2*FCE bf16)
// Aliases: wqkvo_b=mm (dead until fc1 GEMM), fc1b=qb..kb (after attn),
//          fc2b=vt..ao (after wo GEMM).
// ---------------------------------------------------------------------------

typedef __bf16 bf16x8 __attribute__((ext_vector_type(8)));
typedef __bf16 bf16x4 __attribute__((ext_vector_type(4)));
typedef float  f32x4  __attribute__((ext_vector_type(4)));

static __device__ __forceinline__ __bf16 tobf(float f) { return (__bf16)f; }

// async 16B global->LDS; lptr wave-uniform, HW writes lane l at lptr + l*16.
static __device__ __forceinline__ void async_copy16(const void* g, void* l) {
    __builtin_amdgcn_global_load_lds(
        (const __attribute__((address_space(1))) void*)g,
        (__attribute__((address_space(3))) void*)l, 16, 0, 0);
}

// memory-clobber pins memory ops to their phase; register-only MFMA stays
// schedulable (R3->R4 lesson: NO sched_barrier here).
#define LGKM0_FENCE()  asm volatile("s_waitcnt lgkmcnt(0)" ::: "memory")
#define VMCNT8_FENCE() asm volatile("s_waitcnt vmcnt(8)" ::: "memory")
#define VMCNT0_FENCE() asm volatile("s_waitcnt vmcnt(0)" ::: "memory")
// compiler-only fence: blocks LLVM memory-op motion, emits no instruction.
#define CFENCE()       asm volatile("" ::: "memory")

// ---------------------------------------------------------------------------
__global__ void detect_dtype_kernel(const unsigned short* __restrict__ xh,
                                    int* __restrict__ flag) {
    int t = threadIdx.x;                       // one wave of 64
    unsigned short u = xh[2 * t];              // even ushort slots
    int e = (u >> 7) & 0xFF;                   // bf16 exponent field
    bool outlier = (e < 100) || (e > 131);     // implausible for N(0,1)
    unsigned long long m = __ballot(outlier);
    if (t == 0) *flag = (__popcll(m) >= 16) ? 1 : 0;   // 1 => fp32 buffers
}

// ---------------------------------------------------------------------------
// Weight conversion, 8 elems/thread.
__global__ __launch_bounds__(256) void convert_w4(
    const void* __restrict__ w0, const void* __restrict__ w1,
    const void* __restrict__ w2, const void* __restrict__ w3,
    __bf16* __restrict__ dqkvo, const int* __restrict__ flagp) {
    constexpr size_t CC = (size_t)2048 * 2048;
    const int y = blockIdx.y;
    size_t i = ((size_t)blockIdx.x * 256 + threadIdx.x) * 8;
    const void* s = (y == 0) ? w0 : (y == 1) ? w1 : (y == 2) ? w2 : w3;
    __bf16* d = dqkvo + (size_t)y * CC;
    if (*flagp != 0) {
        const float4* sp = (const float4*)((const float*)s + i);
        float4 a = sp[0], b = sp[1];
        bf16x8 o = {tobf(a.x), tobf(a.y), tobf(a.z), tobf(a.w),
                    tobf(b.x), tobf(b.y), tobf(b.z), tobf(b.w)};
        *(bf16x8*)(d + i) = o;
    } else {
        *(bf16x8*)(d + i) = *(const bf16x8*)((const __bf16*)s + i);
    }
}

__global__ __launch_bounds__(256) void convert_w1(
    const void* __restrict__ src, __bf16* __restrict__ dst,
    const int* __restrict__ flagp) {
    size_t i = ((size_t)blockIdx.x * 256 + threadIdx.x) * 8;
    if (*flagp != 0) {
        const float4* sp = (const float4*)((const float*)src + i);
        float4 a = sp[0], b = sp[1];
        bf16x8 o = {tobf(a.x), tobf(a.y), tobf(a.z), tobf(a.w),
                    tobf(b.x), tobf(b.y), tobf(b.z), tobf(b.w)};
        *(bf16x8*)(dst + i) = o;
    } else {
        *(bf16x8*)(dst + i) = *(const bf16x8*)((const __bf16*)src + i);
    }
}

// ---------------------------------------------------------------------------
// rmsnorm: row of C=2048, one block per row, 256 threads x 8 elements.
template <int SRC>
__global__ __launch_bounds__(256) void rmsnorm_kernel(
    const void* __restrict__ xp, __bf16* __restrict__ h,
    const int* __restrict__ flagp) {
    constexpr int C = 2048;
    const int row = blockIdx.x, t = threadIdx.x;
    float vals[8];
    bool f32in = (SRC == 1) || (*flagp != 0);
    if (f32in) {
        const float4* xr = (const float4*)((const float*)xp + (size_t)row * C);
        float4 a = xr[2 * t], b = xr[2 * t + 1];
        vals[0] = a.x; vals[1] = a.y; vals[2] = a.z; vals[3] = a.w;
        vals[4] = b.x; vals[5] = b.y; vals[6] = b.z; vals[7] = b.w;
    } else {
        bf16x8 a = *((const bf16x8*)((const __bf16*)xp + (size_t)row * C) + t);
#pragma unroll
        for (int j = 0; j < 8; ++j) vals[j] = (float)a[j];
    }
    float ss = 0.f;
#pragma unroll
    for (int j = 0; j < 8; ++j) ss += vals[j] * vals[j];
#pragma unroll
    for (int off = 32; off > 0; off >>= 1) ss += __shfl_down(ss, off);
    __shared__ float red[4];
    if ((t & 63) == 0) red[t >> 6] = ss;
    __syncthreads();
    float mean = (red[0] + red[1] + red[2] + red[3]) * (1.0f / C);
    float sc = rsqrtf(mean + 1e-5f);
    bf16x8 o;
#pragma unroll
    for (int j = 0; j < 8; ++j) o[j] = tobf(vals[j] * sc);
    *((bf16x8*)(h + (size_t)row * C) + t) = o;
}

// ---------------------------------------------------------------------------
// Prefetch double-buffered 128x128 2-phase core (proven R7: 875 TF), now with
// kk-interleaved compute: read kk0 frags -> mfma kk0 -> read kk1 -> mfma kk1.
// Halves the front-loaded LDS burst so the LDS pipe overlaps the matrix pipe.
// Hazard reasoning identical to R7 (vmcnt(8) mid-loop / vmcnt(0) last tile /
// CFENCE around barriers since s_barrier intrinsic is IntrNoMem).
static __device__ __forceinline__ void gemm_core_128pf(
    const __bf16* __restrict__ A, const __bf16* __restrict__ W,
    int m0, int n0, int K,
    __bf16 (*As)[128][64], __bf16 (*Bs)[128][64], f32x4 (&acc)[4][4]) {
    const int t = threadIdx.x;
    const int wave = t >> 6, lane = t & 63;
    const int lr = lane & 15, lq = lane >> 4;
    const int wm = wave & 1, wn = wave >> 1;
    const int sx = lr & 7;
    const int NT = K >> 6;

    const __bf16* gA[4];
    const __bf16* gB[4];
    int lo[4];
#pragma unroll
    for (int i = 0; i < 4; ++i) {
        int c = i * 256 + t;
        int row = c >> 3;
        int sl = (c & 7) ^ (row & 7);
        gA[i] = A + (size_t)(m0 + row) * K + sl * 8;
        gB[i] = W + (size_t)(n0 + row) * K + sl * 8;
        lo[i] = (c & ~63) * 8;
    }

    const f32x4 zero = {0.f, 0.f, 0.f, 0.f};
#pragma unroll
    for (int i = 0; i < 4; ++i)
#pragma unroll
        for (int j = 0; j < 4; ++j) acc[i][j] = zero;

    // prologue: stage tile 0 -> buf 0
#pragma unroll
    for (int i = 0; i < 4; ++i) {
        async_copy16(gA[i], &As[0][0][0] + lo[i]);
        async_copy16(gB[i], &Bs[0][0][0] + lo[i]);
    }

    for (int tt = 0; tt < NT; ++tt) {
        const int cur = tt & 1;
        if (tt + 1 < NT) {                       // block-uniform branch
            const int k1 = (tt + 1) * 64;
#pragma unroll
            for (int i = 0; i < 4; ++i) {
                async_copy16(gA[i] + k1, &As[cur ^ 1][0][0] + lo[i]);
                async_copy16(gB[i] + k1, &Bs[cur ^ 1][0][0] + lo[i]);
            }
            VMCNT8_FENCE();                      // tile tt landed (8 newest ok)
        } else {
            VMCNT0_FENCE();                      // drain final tile
        }
        __builtin_amdgcn_s_barrier();            // ... and chip-wide
        CFENCE();                                // reads stay below barrier

#pragma unroll
        for (int kk = 0; kk < 2; ++kk) {         // kk-interleave: read, mfma
            const int sp = ((kk * 4 + lq) ^ sx) * 8;
            bf16x8 a[4], b[4];
#pragma unroll
            for (int ii = 0; ii < 4; ++ii) {
                a[ii] = *(const bf16x8*)&As[cur][wm * 64 + ii * 16 + lr][sp];
                b[ii] = *(const bf16x8*)&Bs[cur][wn * 64 + ii * 16 + lr][sp];
            }
#pragma unroll
            for (int ii = 0; ii < 4; ++ii)
#pragma unroll
                for (int jj = 0; jj < 4; ++jj)
                    acc[ii][jj] = __builtin_amdgcn_mfma_f32_16x16x32_bf16(
                        a[ii], b[jj], acc[ii][jj], 0, 0, 0);
        }
        CFENCE();                                // reads stay above barrier
        __builtin_amdgcn_s_barrier();            // reads done before overwrite
        CFENCE();                                // next stage stays below
    }
}

// 128^2 prefetch NT GEMM with m204-bijective XCD swizzle (nwg%8==0 required;
// wo and fc2 grids are both 512). Launch ids == x (mod 8) land on XCD x; the
// remap gives XCD x the contiguous tile run [x*nwg/8, (x+1)*nwg/8) -> 4
// shared A-panels per XCD, live K-slices L2-resident.
// EPI 5: fp32 out=acc+res (wo); EPI 6: out=acc+res_f32, dtype per flag (fc2).
template <int EPI>
__global__ __launch_bounds__(256) void gemm_nt(
    const __bf16* __restrict__ A, const __bf16* __restrict__ W,
    void* __restrict__ outp, const void* __restrict__ resp,
    int M, int N, int K, const int* __restrict__ flagp) {
    __shared__ __align__(16) __bf16 As[2][128][64];
    __shared__ __align__(16) __bf16 Bs[2][128][64];
    const int t = threadIdx.x;
    const int wave = t >> 6, lane = t & 63;
    const int lr = lane & 15, lq = lane >> 4;
    const int wm = wave & 1, wn = wave >> 1;
    const int id  = blockIdx.x + gridDim.x * blockIdx.y;
    const int nwg = gridDim.x * gridDim.y;
    const int swz = (id & 7) * (nwg >> 3) + (id >> 3);   // bijective, nwg%8==0
    const int m0 = (swz / gridDim.x) * 128, n0 = (swz % gridDim.x) * 128;

    f32x4 acc[4][4];
    gemm_core_128pf(A, W, m0, n0, K, As, Bs, acc);

    const bool f32 = (*flagp != 0);
#pragma unroll
    for (int i = 0; i < 4; ++i)
#pragma unroll
        for (int j = 0; j < 4; ++j)
#pragma unroll
            for (int r = 0; r < 4; ++r) {
                int row = m0 + wm * 64 + i * 16 + lq * 4 + r;
                int col = n0 + wn * 64 + j * 16 + lr;
                size_t o = (size_t)row * N + col;
                float v = acc[i][j][r];
                if (EPI == 5) {
                    float res = f32 ? ((const float*)resp)[o]
                                    : (float)((const __bf16*)resp)[o];
                    ((float*)outp)[o] = v + res;
                } else {  // EPI 6
                    float ov = v + ((const float*)resp)[o];
                    if (f32) ((float*)outp)[o] = ov;
                    else     ((__bf16*)outp)[o] = tobf(ov);
                }
            }
}

// ---------------------------------------------------------------------------
// Fused QKV GEMM on the prefetch 128^2 core: grid (48, 32), 1536 blocks =
// 6.0 perfect dispatch rounds. which = bx>>4 selects weight/output.
// Q pre-scaled by log2(e)/sqrt(HD); V stored transposed.
__global__ __launch_bounds__(256) void gemm_qkv(
    const __bf16* __restrict__ A, const __bf16* __restrict__ Wall,
    __bf16* __restrict__ qout, __bf16* __restrict__ kout,
    __bf16* __restrict__ vtout) {
    constexpr int N = 2048, K = 2048;
    constexpr float kQScale = 1.4426950408889634f * 0.08838834764831845f;
    __shared__ __align__(16) __bf16 As[2][128][64];
    __shared__ __align__(16) __bf16 Bs[2][128][64];
    const int t = threadIdx.x;
    const int wave = t >> 6, lane = t & 63;
    const int lr = lane & 15, lq = lane >> 4;
    const int wm = wave & 1, wn = wave >> 1;
    const int which = blockIdx.x >> 4;
    const int m0 = blockIdx.y * 128, n0 = (blockIdx.x & 15) * 128;
    const __bf16* W = Wall + (size_t)which * N * K;

    f32x4 acc[4][4];
    gemm_core_128pf(A, W, m0, n0, K, As, Bs, acc);

    if (which < 2) {
        __bf16* outp = (which == 0) ? qout : kout;
        const float sc = (which == 0) ? kQScale : 1.0f;
#pragma unroll
        for (int i = 0; i < 4; ++i)
#pragma unroll
            for (int j = 0; j < 4; ++j)
#pragma unroll
                for (int r = 0; r < 4; ++r) {
                    int row = m0 + wm * 64 + i * 16 + lq * 4 + r;
                    int col = n0 + wn * 64 + j * 16 + lr;
                    outp[(size_t)row * N + col] = tobf(acc[i][j][r] * sc);
                }
    } else {
#pragma unroll
        for (int i = 0; i < 4; ++i)
#pragma unroll
            for (int j = 0; j < 4; ++j) {
                int t0 = m0 + wm * 64 + i * 16 + lq * 4;   // 4 consec tokens
                int b  = t0 >> 11, tt = t0 & 2047;
                int col = n0 + wn * 64 + j * 16 + lr;      // h*128 + d
                bf16x4 p = {tobf(acc[i][j][0]), tobf(acc[i][j][1]),
                            tobf(acc[i][j][2]), tobf(acc[i][j][3])};
                *(bf16x4*)(vtout + (((size_t)(b * 2048 + col)) << 11) + tt) = p;
            }
    }
}

// ---------------------------------------------------------------------------
// 256x256 8-phase core (validated R4-R7, UNCHANGED). 512 threads = 8 waves.
static __device__ __forceinline__ void gemm_core_256(
    const __bf16* __restrict__ A, const __bf16* __restrict__ W,
    int m0, int n0, int K,
    __bf16 (*As)[256][64], __bf16 (*Bs)[256][64], f32x4 (&acc)[8][4]) {
    const int tid = threadIdx.x;
    const int wave = tid >> 6, lane = tid & 63;
    const int lr = lane & 15, lq = lane >> 4;
    const int wm = wave >> 2, wn = wave & 3;
    const int sx = lr & 7;
    const int NT = K >> 6;

    int off[4], lo[4];
#pragma unroll
    for (int i = 0; i < 4; ++i) {
        int c = i * 512 + tid;
        int row = c >> 3;
        off[i] = row * K + (((c & 7) ^ (row & 7)) * 8);
        lo[i] = (c & ~63) * 8;
    }

    const f32x4 zero = {0.f, 0.f, 0.f, 0.f};
#pragma unroll
    for (int m = 0; m < 8; ++m)
#pragma unroll
        for (int n = 0; n < 4; ++n) acc[m][n] = zero;

#pragma unroll
    for (int pt = 0; pt < 2; ++pt) {
        const __bf16* ga = A + (size_t)m0 * K + pt * 64;
        const __bf16* gb = W + (size_t)n0 * K + pt * 64;
#pragma unroll
        for (int i = 0; i < 4; ++i)
            async_copy16(ga + off[i], &As[pt][0][0] + lo[i]);
#pragma unroll
        for (int i = 0; i < 4; ++i)
            async_copy16(gb + off[i], &Bs[pt][0][0] + lo[i]);
    }
    VMCNT8_FENCE();
    __builtin_amdgcn_s_barrier();

    for (int t = 0; t < NT; ++t) {
        const int bi = t & 1;
        const __bf16 (*Ac)[64] = As[bi];
        const __bf16 (*Bc)[64] = Bs[bi];
        const int ts = (t + 2 < NT) ? t + 2 : NT - 1;   // clamp: safe dummy
        const __bf16* gAt = A + (size_t)m0 * K + (size_t)ts * 64;
        const __bf16* gBt = W + (size_t)n0 * K + (size_t)ts * 64;

        bf16x8 a0[4][2], a1[4][2], b0[2][2], b1[2][2];

        // ---- Q0: read a0 (m0-3) + b0 (n0-1); mfma a0 x b0 ----
#pragma unroll
        for (int m = 0; m < 4; ++m)
#pragma unroll
            for (int kk = 0; kk < 2; ++kk)
                a0[m][kk] = *(const bf16x8*)
                    &Ac[wm * 128 + m * 16 + lr][((kk * 4 + lq) ^ sx) * 8];
#pragma unroll
        for (int n = 0; n < 2; ++n)
#pragma unroll
            for (int kk = 0; kk < 2; ++kk)
                b0[n][kk] = *(const bf16x8*)
                    &Bc[wn * 64 + n * 16 + lr][((kk * 4 + lq) ^ sx) * 8];
        __builtin_amdgcn_s_barrier();
        LGKM0_FENCE();
        __builtin_amdgcn_s_setprio(1);
#pragma unroll
        for (int m = 0; m < 4; ++m)
#pragma unroll
            for (int n = 0; n < 2; ++n)
#pragma unroll
                for (int kk = 0; kk < 2; ++kk)
                    acc[m][n] = __builtin_amdgcn_mfma_f32_16x16x32_bf16(
                        a0[m][kk], b0[n][kk], acc[m][n], 0, 0, 0);
        __builtin_amdgcn_s_setprio(0);
        __builtin_amdgcn_s_barrier();

        // ---- Q1: read a1 (m4-7); mfma a1 x b0 ----
#pragma unroll
        for (int m = 0; m < 4; ++m)
#pragma unroll
            for (int kk = 0; kk < 2; ++kk)
                a1[m][kk] = *(const bf16x8*)
                    &Ac[wm * 128 + (m + 4) * 16 + lr][((kk * 4 + lq) ^ sx) * 8];
        __builtin_amdgcn_s_barrier();
        LGKM0_FENCE();
        __builtin_amdgcn_s_setprio(1);
#pragma unroll
        for (int m = 0; m < 4; ++m)
#pragma unroll
            for (int n = 0; n < 2; ++n)
#pragma unroll
                for (int kk = 0; kk < 2; ++kk)
                    acc[m + 4][n] = __builtin_amdgcn_mfma_f32_16x16x32_bf16(
                        a1[m][kk], b0[n][kk], acc[m + 4][n], 0, 0, 0);
        __builtin_amdgcn_s_setprio(0);
        __builtin_amdgcn_s_barrier();
        // (A rows of tile t ds_read-complete chip-wide here)

        // ---- Q2: read b1 (n2-3); stage A(t+2)->bi; mfma a1 x b1 ----
#pragma unroll
        for (int n = 0; n < 2; ++n)
#pragma unroll
            for (int kk = 0; kk < 2; ++kk)
                b1[n][kk] = *(const bf16x8*)
                    &Bc[wn * 64 + (n + 2) * 16 + lr][((kk * 4 + lq) ^ sx) * 8];
#pragma unroll
        for (int i = 0; i < 4; ++i)
            async_copy16(gAt + off[i], &As[bi][0][0] + lo[i]);
        __builtin_amdgcn_s_barrier();
        LGKM0_FENCE();
        __builtin_amdgcn_s_setprio(1);
#pragma unroll
        for (int m = 0; m < 4; ++m)
#pragma unroll
            for (int n = 0; n < 2; ++n)
#pragma unroll
                for (int kk = 0; kk < 2; ++kk)
                    acc[m + 4][n + 2] = __builtin_amdgcn_mfma_f32_16x16x32_bf16(
                        a1[m][kk], b1[n][kk], acc[m + 4][n + 2], 0, 0, 0);
        __builtin_amdgcn_s_setprio(0);
        __builtin_amdgcn_s_barrier();
        // (B rows of tile t ds_read-complete chip-wide here)

        // ---- Q3: stage B(t+2)->bi; mfma a0 x b1; counted vmcnt ----
#pragma unroll
        for (int i = 0; i < 4; ++i)
            async_copy16(gBt + off[i], &Bs[bi][0][0] + lo[i]);
        __builtin_amdgcn_s_barrier();
        __builtin_amdgcn_s_setprio(1);
#pragma unroll
        for (int m = 0; m < 4; ++m)
#pragma unroll
            for (int n = 0; n < 2; ++n)
#pragma unroll
                for (int kk = 0; kk < 2; ++kk)
                    acc[m][n + 2] = __builtin_amdgcn_mfma_f32_16x16x32_bf16(
                        a0[m][kk], b1[n][kk], acc[m][n + 2], 0, 0, 0);
        __builtin_amdgcn_s_setprio(0);
        VMCNT8_FENCE();   // tile t+1 fully landed; t+2's 8 loads stay in flight
        __builtin_amdgcn_s_barrier();
    }
}

// 256^2 NT GEMM (8-phase). EPI 2: bf16 relu(acc)^2 (fc1).
template <int EPI>
__global__ __launch_bounds__(512, 1) void gemm256_nt(
    const __bf16* __restrict__ A, const __bf16* __restrict__ W,
    void* __restrict__ outp, const void* __restrict__ resp,
    int M, int N, int K, const int* __restrict__ flagp) {
    __shared__ __align__(16) __bf16 As[2][256][64];
    __shared__ __align__(16) __bf16 Bs[2][256][64];
    const int tid = threadIdx.x;
    const int wave = tid >> 6, lane = tid & 63;
    const int lr = lane & 15, lq = lane >> 4;
    const int wm = wave >> 2, wn = wave & 3;
    const int m0 = blockIdx.y * 256, n0 = blockIdx.x * 256;

    f32x4 acc[8][4];
    gemm_core_256(A, W, m0, n0, K, As, Bs, acc);

    const bool f32 = (EPI == 2) ? false : (*flagp != 0);
#pragma unroll
    for (int m = 0; m < 8; ++m)
#pragma unroll
        for (int n = 0; n < 4; ++n)
#pragma unroll
            for (int r = 0; r < 4; ++r) {
                int row = m0 + wm * 128 + m * 16 + lq * 4 + r;
                int col = n0 + wn * 64 + n * 16 + lr;
                size_t o = (size_t)row * N + col;
                float v = acc[m][n][r];
                if (EPI == 2) {
                    float rv = v > 0.f ? v : 0.f;
                    ((__bf16*)outp)[o] = tobf(rv * rv);
                } else if (EPI == 5) {
                    float res = f32 ? ((const float*)resp)[o]
                                    : (float)((const __bf16*)resp)[o];
                    ((float*)outp)[o] = v + res;
                } else {  // EPI 6
                    float ov = v + ((const float*)resp)[o];
                    if (f32) ((float*)outp)[o] = ov;
                    else     ((__bf16*)outp)[o] = tobf(ov);
                }
            }
}

// ---------------------------------------------------------------------------
// Causal flash attention + T14 async-stage split: kb+1's K/V global loads
// issue right after kb's LDS writes + barrier; the ~900cy HBM latency hides
// under QK+softmax+PV. Regs: +8 bf16x8 (32 VGPR). Grid (16, H, B), 4 waves.
__global__ __launch_bounds__(256) void attn_kernel(
    const __bf16* __restrict__ Q, const __bf16* __restrict__ K,
    const __bf16* __restrict__ Vt, __bf16* __restrict__ O) {
    constexpr int T = 2048, C = 2048, HD = 128;
    __shared__ __align__(16) __bf16 Ks[64][136];
    __shared__ __align__(16) __bf16 Vts[128][72];
    __shared__ __align__(16) __bf16 Ps[4][16][72];
    const int t = threadIdx.x, w = t >> 6, lane = t & 63;
    const int lr = lane & 15, lq = lane >> 4;
    const int b = blockIdx.z, h = blockIdx.y;
    const __bf16* vtb = Vt + ((size_t)(b * 2048 + h * 128) << 11);
    const f32x4 zero = {0.f, 0.f, 0.f, 0.f};

    // per-thread staging coordinates (fixed across iterations)
    const int kr[4] = {t >> 4, (t + 256) >> 4, (t + 512) >> 4, (t + 768) >> 4};
    const int kc = (t & 15) * 8;
    const int vr[4] = {t >> 3, (t + 256) >> 3, (t + 512) >> 3, (t + 768) >> 3};
    const int vc = (t & 7) * 8;

    bf16x8 ones;
#pragma unroll
    for (int j = 0; j < 8; ++j) ones[j] = (lr == 0) ? (__bf16)1.0f : (__bf16)0.0f;

    for (int pass = 0; pass < 2; ++pass) {
        const int qblk = (pass == 0) ? blockIdx.x : 31 - blockIdx.x;
        const int q0 = qblk * 64;

        const int qrow = q0 + w * 16 + lr;
        const __bf16* qb = Q + (size_t)(b * T + qrow) * C + h * HD;
        bf16x8 qf[4];
#pragma unroll
        for (int s = 0; s < 4; ++s)
            qf[s] = *(const bf16x8*)(qb + s * 32 + lq * 8);

        f32x4 oacc[8], lacc = zero;
#pragma unroll
        for (int nc = 0; nc < 8; ++nc) oacc[nc] = zero;
        float m_i[4] = {-3e38f, -3e38f, -3e38f, -3e38f};

        // T14 prologue: load kb=0 K/V slices into regs
        bf16x8 kreg[4], vreg[4];
#pragma unroll
        for (int i = 0; i < 4; ++i)
            kreg[i] = *(const bf16x8*)(K + (size_t)(b * T + kr[i]) * C + h * HD + kc);
#pragma unroll
        for (int i = 0; i < 4; ++i)
            vreg[i] = *(const bf16x8*)(vtb + ((size_t)vr[i] << 11) + vc);

        for (int kb = 0; kb <= qblk; ++kb) {
            // write staged regs to LDS (compiler inserts vmcnt before use)
#pragma unroll
            for (int i = 0; i < 4; ++i) *(bf16x8*)&Ks[kr[i]][kc] = kreg[i];
#pragma unroll
            for (int i = 0; i < 4; ++i) *(bf16x8*)&Vts[vr[i]][vc] = vreg[i];
            __syncthreads();

            // T14: issue kb+1 loads now; latency hides under QK+softmax+PV
            if (kb < qblk) {
                const int k01 = (kb + 1) * 64;
#pragma unroll
                for (int i = 0; i < 4; ++i)
                    kreg[i] = *(const bf16x8*)(K + (size_t)(b * T + k01 + kr[i]) * C
                                               + h * HD + kc);
#pragma unroll
                for (int i = 0; i < 4; ++i)
                    vreg[i] = *(const bf16x8*)(vtb + ((size_t)vr[i] << 11) + k01 + vc);
            }

            float pv[4][4];
#pragma unroll
            for (int jc = 0; jc < 4; ++jc) {
                f32x4 s = zero;
#pragma unroll
                for (int ks = 0; ks < 4; ++ks) {
                    bf16x8 kf = *(const bf16x8*)&Ks[jc * 16 + lr][ks * 32 + lq * 8];
                    s = __builtin_amdgcn_mfma_f32_16x16x32_bf16(qf[ks], kf, s, 0, 0, 0);
                }
#pragma unroll
                for (int r = 0; r < 4; ++r) pv[jc][r] = s[r];
            }
            if (kb == qblk) {   // diagonal: causal mask (wave-uniform branch)
#pragma unroll
                for (int jc = 0; jc < 4; ++jc)
#pragma unroll
                    for (int r = 0; r < 4; ++r)
                        if (jc * 16 + lr > w * 16 + lq * 4 + r) pv[jc][r] = -3e38f;
            }
            float rmax[4];
#pragma unroll
            for (int r = 0; r < 4; ++r)
                rmax[r] = fmaxf(fmaxf(pv[0][r], pv[1][r]), fmaxf(pv[2][r], pv[3][r]));
#pragma unroll
            for (int off = 1; off < 16; off <<= 1)
#pragma unroll
                for (int r = 0; r < 4; ++r)
                    rmax[r] = fmaxf(rmax[r], __shfl_xor(rmax[r], off));
            float alpha[4];
#pragma unroll
            for (int r = 0; r < 4; ++r) {
                float mn = fmaxf(m_i[r], rmax[r]);
                alpha[r] = exp2f(m_i[r] - mn);
                m_i[r] = mn;
            }
#pragma unroll
            for (int jc = 0; jc < 4; ++jc)
#pragma unroll
                for (int r = 0; r < 4; ++r)
                    Ps[w][lq * 4 + r][jc * 16 + lr] = tobf(exp2f(pv[jc][r] - m_i[r]));
#pragma unroll
            for (int nc = 0; nc < 8; ++nc)
#pragma unroll
                for (int r = 0; r < 4; ++r) oacc[nc][r] *= alpha[r];
#pragma unroll
            for (int r = 0; r < 4; ++r) lacc[r] *= alpha[r];
            __syncthreads();   // P visible before PV reads

#pragma unroll
            for (int s2 = 0; s2 < 2; ++s2) {
                bf16x8 pa = *(const bf16x8*)&Ps[w][lr][s2 * 32 + lq * 8];
#pragma unroll
                for (int nc = 0; nc < 8; ++nc) {
                    bf16x8 vf = *(const bf16x8*)&Vts[nc * 16 + lr][s2 * 32 + lq * 8];
                    oacc[nc] = __builtin_amdgcn_mfma_f32_16x16x32_bf16(
                        pa, vf, oacc[nc], 0, 0, 0);
                }
                lacc = __builtin_amdgcn_mfma_f32_16x16x32_bf16(pa, ones, lacc, 0, 0, 0);
            }
            __syncthreads();   // PV reads done before next staging overwrite
        }

        // l lives in lanes lr==0 (col 0); broadcast within the 16-lane row group
        float inv[4];
#pragma unroll
        for (int r = 0; r < 4; ++r) inv[r] = 1.0f / __shfl(lacc[r], lane & 48);
#pragma unroll
        for (int nc = 0; nc < 8; ++nc)
#pragma unroll
            for (int r = 0; r < 4; ++r) {
                int row = q0 + w * 16 + lq * 4 + r;
                O[(size_t)(b * T + row) * C + h * HD + nc * 16 + lr] =
                    tobf(oacc[nc][r] * inv[r]);
            }
        __syncthreads();       // pass-1 staging must not race pass-0 epilogue
    }
}

// ---------------------------------------------------------------------------
extern "C" void kernel_launch(void* const* d_in, const int* in_sizes, int n_in,
                              void* d_out, int out_size, void* d_ws, size_t ws_size,
                              hipStream_t stream) {
    const void* x   = d_in[0];
    const void* wq  = d_in[1];
    const void* wk  = d_in[2];
    const void* wv  = d_in[3];
    const void* wo  = d_in[4];
    const void* fc1 = d_in[5];
    const void* fc2 = d_in[6];
    constexpr int Bv = 2, Tv = 2048, Cv = 2048, Hv = 16, MLP = 8192;
    constexpr int M = Bv * Tv;                  // 4096 rows
    constexpr size_t NE = (size_t)M * Cv;       // 8,388,608
    constexpr size_t CC = (size_t)Cv * Cv;      // 4,194,304

    char* ws = (char*)d_ws;
    int*    flag = (int*)ws;                    // 256 B reserved
    __bf16* h    = (__bf16*)(ws + 256);         // NE bf16
    __bf16* qb   = h  + NE;                     // NE bf16
    __bf16* kb   = qb + NE;                     // NE bf16
    __bf16* vt   = kb + NE;                     // NE bf16 (V, pre-transposed)
    __bf16* ao   = vt + NE;                     // NE bf16
    float*  x1   = (float*)(ao + NE);           // NE fp32
    __bf16* mm   = (__bf16*)(x1 + NE);          // M*MLP bf16 (67.1 MB)
    // lifetime aliases:
    __bf16* wqkvob = mm;   // 4*CC bf16, dead before fc1 GEMM writes mm
    __bf16* fc1b   = qb;   // FCE bf16 = qb+kb, converted after attn
    __bf16* fc2b   = vt;   // FCE bf16 = vt+ao, converted after wo GEMM

    detect_dtype_kernel<<<1, 64, 0, stream>>>((const unsigned short*)x, flag);

    convert_w4<<<dim3(2048, 4), 256, 0, stream>>>(wq, wk, wv, wo, wqkvob, flag);

    rmsnorm_kernel<0><<<M, 256, 0, stream>>>(x, h, flag);

    // qkv (prefetch 128^2): 1536 blocks = 6.0 perfect rounds
    gemm_qkv<<<dim3(48, 32), 256, 0, stream>>>(h, wqkvob, qb, kb, vt);

    attn_kernel<<<dim3(16, Hv, Bv), 256, 0, stream>>>(qb, kb, vt, ao);

    // fc1 -> bf16 into qb+kb (dead after attn)
    convert_w1<<<8192, 256, 0, stream>>>(fc1, fc1b, flag);

    // wo (prefetch 128^2 + XCD swizzle, 512 blocks): x1 = ao @ wo^T + x
    gemm_nt<5><<<dim3(16, 32), 256, 0, stream>>>(ao, wqkvob + 3 * CC, x1, x,
                                                 M, Cv, Cv, flag);

    // fc2 -> bf16 into vt+ao (dead after wo GEMM)
    convert_w1<<<8192, 256, 0, stream>>>(fc2, fc2b, flag);

    rmsnorm_kernel<1><<<M, 256, 0, stream>>>(x1, h, flag);

    // fc1 (256^2 8-phase, 512 blocks = 2.0 rounds): mm = relu(h @ fc1^T)^2
    gemm256_nt<2><<<dim3(32, 16), 512, 0, stream>>>(h, fc1b, mm, nullptr,
                                                    M, MLP, Cv, flag);

    // fc2 (prefetch 128^2 + XCD swizzle, 512 blocks): d_out = mm @ fc2^T + x1
    gemm_nt<6><<<dim3(16, 32), 256, 0, stream>>>(mm, fc2b, d_out, x1,
                                                 M, Cv, MLP, flag);
}